// Round 5
// baseline (1057.178 us; speedup 1.0000x reference)
//
#include <hip/hip_runtime.h>

// LSTM: SEQ=4096, BATCH=4096, IN=2, HID=8, fp32.
// R5: L=32 lanes/elem, unit-major (lane = 4u+q) -> 2048 waves = 2 waves/SIMD
// so the second wave hides the serial-chain stalls that capped R4 (1 wave/SIMD,
// 61% busy + 39% exposed latency). Lane owns ONE gate row (q of unit u).
//   - gates of unit u live in one quad -> quad_perm broadcast, no selection
//   - h all-gather: xor4/xor8/xor12 via DPP; xor16 via v_permlane16_swap_b32
//     (gfx950 VALU cross-row swap; ds_swizzle 0x401F fallback)
//   - c/h update replicated across the quad (issue cost is lane-independent)

#define SEQ   4096
#define BATCH 4096
#define PF    8

#define DPP_QX3   0x1B  // quad_perm [3,2,1,0] = lane ^ 3
#define DPP_ROR8  0x128 // row_ror:8           = lane ^ 8 (within 16-row)
#define DPP_HMIR  0x141 // row_half_mirror     = lane ^ 7
#define DPP_BC0   0x00  // quad_perm [0,0,0,0] -> gate i (q=0)
#define DPP_BC1   0x55  // quad_perm [1,1,1,1] -> gate f
#define DPP_BC2   0xAA  // quad_perm [2,2,2,2] -> gate g~
#define DPP_BC3   0xFF  // quad_perm [3,3,3,3] -> gate o

template<int CTRL>
__device__ __forceinline__ float dppf(float v) {
    int i = __builtin_bit_cast(int, v);
    int r = __builtin_amdgcn_update_dpp(i, i, CTRL, 0xf, 0xf, false);
    return __builtin_bit_cast(float, r);
}
__device__ __forceinline__ float xor4f(float v) {   // lane ^ 4 = (^7)^3
    return dppf<DPP_QX3>(dppf<DPP_HMIR>(v));
}
__device__ __forceinline__ float xor8f(float v) { return dppf<DPP_ROR8>(v); }

#if __has_builtin(__builtin_amdgcn_permlane16_swap)
typedef unsigned int u32x2 __attribute__((ext_vector_type(2)));
__device__ __forceinline__ float xor16f(float v, bool oddrow) {
    unsigned int iv = __builtin_bit_cast(unsigned int, v);
    u32x2 r = __builtin_amdgcn_permlane16_swap(iv, iv, false, false);
    // after swap: r.x = {r0,r0,r2,r2}, r.y = {r1,r1,r3,r3} (16-lane rows)
    unsigned int s = oddrow ? r.x : r.y;
    return __builtin_bit_cast(float, s);
}
#else
__device__ __forceinline__ float xor16f(float v, bool) {
    int iv = __builtin_bit_cast(int, v);
    int r = __builtin_amdgcn_ds_swizzle(iv, 0x401F);  // bit-mode xor 0x10
    return __builtin_bit_cast(float, r);
}
#endif

__global__ __launch_bounds__(256, 2) void lstm_kernel(
    const float* __restrict__ x,    // (SEQ, BATCH, 2)
    const float* __restrict__ h0,   // (1, BATCH, 8)
    const float* __restrict__ c0,   // (1, BATCH, 8)
    const float* __restrict__ Wih,  // (32, 2)
    const float* __restrict__ Whh,  // (32, 8)
    const float* __restrict__ bih,  // (32)
    const float* __restrict__ bhh,  // (32)
    float* __restrict__ out)        // (1, BATCH, 8)
{
    const int tid  = threadIdx.x;
    const int l32  = tid & 31;       // lane within 32-lane element group
    const int u    = l32 >> 2;       // unit 0..7 (bits 2..4 of lane)
    const int q    = l32 & 3;        // gate: 0=i 1=f 2=g~ 3=o
    const int b    = blockIdx.x * 8 + (tid >> 5);
    const bool oddrow = ((tid & 63) & 16) != 0;   // wave 16-row parity

    const int g = q * 8 + u;         // this lane's gate row in W (4H x *)

    // Whh coeffs in gather (xor-m) order: w[m] multiplies h_{u^m}
    float w[8];
#pragma unroll
    for (int m = 0; m < 8; ++m) w[m] = Whh[g * 8 + (u ^ m)];
    const float wx0  = Wih[2 * g], wx1 = Wih[2 * g + 1];
    const float bias = bih[g] + bhh[g];

    // activation constants: sigmoid(p)=1/(1+exp2(-p*log2e)); tanh=2*sig(2p)-1
    const float LOG2E = 1.4426950408889634f;
    const float tm   = (q == 2) ? 2.0f : 1.0f;
    const float addc = 1.0f - tm;
    const float smul = -LOG2E * tm;
    const float cmul = -2.0f * LOG2E;

    // state: unit u's c,h replicated across the 4 q-lanes of the quad
    float c = c0[b * 8 + u];
    float h = h0[b * 8 + u];

    const float2* __restrict__ xp2 = (const float2*)x;
    float2 xb[PF];
#pragma unroll
    for (int p = 0; p < PF; ++p) xb[p] = xp2[p * BATCH + b];

    for (int s = 0; s < SEQ; s += PF) {
#pragma unroll
        for (int p = 0; p < PF; ++p) {
            const float2 xc = xb[p];
            const int sn = (s + p + PF) & (SEQ - 1);   // uniform wrap
            xb[p] = xp2[sn * BATCH + b];

            // ---- h all-gather: Xm = h_{u^m}
            const float X1 = xor4f(h);
            const float X2 = xor8f(h);
            const float X3 = xor4f(X2);
            const float X4 = xor16f(h, oddrow);
            const float X5 = xor4f(X4);
            const float X6 = xor8f(X4);
            const float X7 = xor4f(X6);

            // ---- gate-row dot product (two accumulator chains)
            float a0 = __builtin_fmaf(xc.x, wx0, bias);
            float a1 = xc.y * wx1;
            a0 = __builtin_fmaf(h,  w[0], a0);
            a1 = __builtin_fmaf(X1, w[1], a1);
            a0 = __builtin_fmaf(X2, w[2], a0);
            a1 = __builtin_fmaf(X3, w[3], a1);
            a0 = __builtin_fmaf(X4, w[4], a0);
            a1 = __builtin_fmaf(X5, w[5], a1);
            a0 = __builtin_fmaf(X6, w[6], a0);
            a1 = __builtin_fmaf(X7, w[7], a1);
            const float pre = a0 + a1;

            // ---- activation (sigmoid or tanh by lane's gate type)
            const float e   = __builtin_amdgcn_exp2f(pre * smul);
            const float r   = __builtin_amdgcn_rcpf(e + 1.0f);
            const float act = __builtin_fmaf(r, tm, addc);

            // ---- gate broadcast within quad (lane 4u+q holds gate q)
            const float gi = dppf<DPP_BC0>(act);
            const float gf = dppf<DPP_BC1>(act);
            const float gg = dppf<DPP_BC2>(act);
            const float go = dppf<DPP_BC3>(act);

            // ---- c/h update (replicated across quad; issue cost identical)
            c = __builtin_fmaf(gf, c, gi * gg);
            const float e2 = __builtin_amdgcn_exp2f(c * cmul);
            const float th = __builtin_fmaf(__builtin_amdgcn_rcpf(e2 + 1.0f),
                                            2.0f, -1.0f);
            h = go * th;
        }
    }

    if (q == 0) out[b * 8 + u] = h;

    (void)l32;
}

extern "C" void kernel_launch(void* const* d_in, const int* in_sizes, int n_in,
                              void* d_out, int out_size, void* d_ws, size_t ws_size,
                              hipStream_t stream) {
    const float* x   = (const float*)d_in[0];
    const float* h0  = (const float*)d_in[1];
    const float* c0  = (const float*)d_in[2];
    const float* Wih = (const float*)d_in[3];
    const float* Whh = (const float*)d_in[4];
    const float* bih = (const float*)d_in[5];
    const float* bhh = (const float*)d_in[6];
    float* out = (float*)d_out;

    dim3 grid(BATCH / 8);    // 512 blocks -> 2048 waves = 2 waves/SIMD
    dim3 block(256);         // 8 elements x 32 lanes
    hipLaunchKernelGGL(lstm_kernel, grid, block, 0, stream,
                       x, h0, c0, Wih, Whh, bih, bhh, out);
}

// Round 6
// 921.336 us; speedup vs baseline: 1.1474x; 1.1474x over previous
//
#include <hip/hip_runtime.h>

// LSTM: SEQ=4096, BATCH=4096, IN=2, HID=8, fp32.
// R6 = R4 (L=16, pair-packed, DPP-only comm, 1024 waves) +
//  (a) activation scales folded into pre-scaled weights/bias (no mul before exp)
//  (b) c kept in scaled space c' = -2*log2e*c  (i-lane emits -2L2E*sigma,
//      o-lane emits 2*sigma) -> tanh(c) = 2*rcp(1+exp2(c')) - 1 with no mul
//  (c) c/h update EXEC-MASKED to q==0 (16/64 lanes) -> the 4 trans instrs
//      in that path run at 1/4 lane occupancy (SFU-occupancy theory), h is
//      re-broadcast with one quad_perm DPP
//  (d) shallower fma tree in the matvec.

#define SEQ   4096
#define BATCH 4096
#define PF    8

#define DPP_QX3   0x1B  // quad_perm [3,2,1,0] = lane ^ 3
#define DPP_ROR8  0x128 // row_ror:8           = lane ^ 8 (within 16-row)
#define DPP_HMIR  0x141 // row_half_mirror     = lane ^ 7
#define DPP_BC0   0x00  // quad_perm [0,0,0,0] -> gate i / h owner (q=0)
#define DPP_BC1   0x55  // quad_perm [1,1,1,1] -> gate f
#define DPP_BC2   0xAA  // quad_perm [2,2,2,2] -> gate g~
#define DPP_BC3   0xFF  // quad_perm [3,3,3,3] -> gate o

typedef float v2f __attribute__((ext_vector_type(2)));

template<int CTRL>
__device__ __forceinline__ float dppf(float v) {
    int i = __builtin_bit_cast(int, v);
    int r = __builtin_amdgcn_update_dpp(i, i, CTRL, 0xf, 0xf, false);
    return __builtin_bit_cast(float, r);
}
template<int CTRL>
__device__ __forceinline__ v2f dpp2(v2f v) {
    v2f r; r.x = dppf<CTRL>(v.x); r.y = dppf<CTRL>(v.y); return r;
}
__device__ __forceinline__ v2f xor4v(v2f v) {   // lane ^ 4 = (^7)^3
    return dpp2<DPP_QX3>(dpp2<DPP_HMIR>(v));
}
__device__ __forceinline__ v2f xor8v(v2f v) { return dpp2<DPP_ROR8>(v); }

__device__ __forceinline__ v2f vfma(v2f a, v2f b, v2f c) {
    return __builtin_elementwise_fma(a, b, c);
}

__global__ __launch_bounds__(256, 1) void lstm_kernel(
    const float* __restrict__ x,    // (SEQ, BATCH, 2)
    const float* __restrict__ h0,   // (1, BATCH, 8)
    const float* __restrict__ c0,   // (1, BATCH, 8)
    const float* __restrict__ Wih,  // (32, 2)
    const float* __restrict__ Whh,  // (32, 8)
    const float* __restrict__ bih,  // (32)
    const float* __restrict__ bhh,  // (32)
    float* __restrict__ out)        // (1, BATCH, 8)
{
    const int tid = threadIdx.x;
    const int l   = tid & 15;        // lane in 16-lane group
    const int q   = l & 3;           // gate: 0=i 1=f 2=g~ 3=o
    const int u   = l >> 2;          // unit-pair: owns units u and u+4
    const int b   = blockIdx.x * 16 + (tid >> 4);

    const int gA = q * 8 + u;        // gate row, unit u
    const int gB = gA + 4;           // gate row, unit u+4

    const float L2E = 1.4426950408889634f;
    // input scale folded into weights: sigmoid rows -L2E, tanh(g~) row -2*L2E
    const float smul = (q == 2) ? (-2.0f * L2E) : (-L2E);
    // finalize act = r*tm + addc per gate:
    //  i: tm=-2*L2E (emit -2L2E*sigma for scaled-c recurrence), addc=0
    //  f: tm=1, addc=0        g~: tm=2, addc=-1 (tanh)       o: tm=2 (2*sigma)
    const float tmv   = (q == 0) ? (-2.0f * L2E) : ((q >= 2) ? 2.0f : 1.0f);
    const float addcv = (q == 2) ? -1.0f : 0.0f;
    const v2f tmP   = { tmv, tmv };
    const v2f addcP = { addcv, addcv };
    const v2f oneP  = { 1.0f, 1.0f };
    const v2f halfN = { -0.5f, -0.5f };

    // Whh pairs in gather (xor-m) order, PRE-SCALED by smul
    v2f WA[4], WB[4];
#pragma unroll
    for (int m = 0; m < 4; ++m) {
        const int k = u ^ m;
        WA[m].x = Whh[gA * 8 + k]     * smul;
        WA[m].y = Whh[gA * 8 + 4 + k] * smul;
        WB[m].x = Whh[gB * 8 + k]     * smul;
        WB[m].y = Whh[gB * 8 + 4 + k] * smul;
    }
    const float wxA0 = Wih[2 * gA] * smul, wxA1 = Wih[2 * gA + 1] * smul;
    const float wxB0 = Wih[2 * gB] * smul, wxB1 = Wih[2 * gB + 1] * smul;
    const float biasA = (bih[gA] + bhh[gA]) * smul;
    const float biasB = (bih[gB] + bhh[gB]) * smul;

    // state: c in scaled space c' = -2*L2E*c (valid only in q==0 lanes);
    // h replicated in all lanes via bcast
    const float cs = -2.0f * L2E;
    v2f cP = { c0[b * 8 + u] * cs, c0[b * 8 + u + 4] * cs };
    v2f hP = { h0[b * 8 + u],      h0[b * 8 + u + 4] };

    const float2* __restrict__ xp2 = (const float2*)x;
    float2 xb[PF];
#pragma unroll
    for (int p = 0; p < PF; ++p) xb[p] = xp2[p * BATCH + b];

    for (int s = 0; s < SEQ; s += PF) {
#pragma unroll
        for (int p = 0; p < PF; ++p) {
            const float2 xc = xb[p];
            const int sn = (s + p + PF) & (SEQ - 1);   // uniform wrap
            xb[p] = xp2[sn * BATCH + b];

            // ---- h all-gather: P[m] = (h_{u^m}, h_{u^m+4})
            const v2f P0 = hP;
            const v2f P1 = xor4v(hP);
            const v2f P2 = xor8v(hP);
            const v2f P3 = xor8v(P1);

            // ---- gate-row dots (weights pre-scaled; shallow tree)
            v2f accA = { __builtin_fmaf(xc.x, wxA0, biasA), xc.y * wxA1 };
            accA = vfma(P0, WA[0], accA);
            accA = vfma(P1, WA[1], accA);
            v2f accA2 = vfma(P3, WA[3], P2 * WA[2]);
            accA = accA + accA2;

            v2f accB = { __builtin_fmaf(xc.x, wxB0, biasB), xc.y * wxB1 };
            accB = vfma(P0, WB[0], accB);
            accB = vfma(P1, WB[1], accB);
            v2f accB2 = vfma(P3, WB[3], P2 * WB[2]);
            accB = accB + accB2;

            const v2f pre = { accA.x + accA.y, accB.x + accB.y };  // already scaled

            // ---- activation: exp2 straight off the dot product
            v2f e; e.x = __builtin_amdgcn_exp2f(pre.x);
                   e.y = __builtin_amdgcn_exp2f(pre.y);
            const v2f d = e + oneP;
            v2f r; r.x = __builtin_amdgcn_rcpf(d.x);
                   r.y = __builtin_amdgcn_rcpf(d.y);
            const v2f act = vfma(r, tmP, addcP);

            // ---- gate broadcast within quad
            const v2f gi  = dpp2<DPP_BC0>(act);   // -2L2E * sigma_i
            const v2f gf  = dpp2<DPP_BC1>(act);   // sigma_f
            const v2f gg  = dpp2<DPP_BC2>(act);   // tanh(g~)
            const v2f go2 = dpp2<DPP_BC3>(act);   // 2 * sigma_o

            // ---- c/h update, MASKED to q==0 (1/4 lane occupancy on SFU)
            if (q == 0) {
                cP = vfma(gf, cP, gi * gg);       // scaled-c recurrence
                const v2f ngoh = go2 * halfN;     // -sigma_o
                v2f e2; e2.x = __builtin_amdgcn_exp2f(cP.x);
                        e2.y = __builtin_amdgcn_exp2f(cP.y);
                const v2f d2 = e2 + oneP;
                v2f r2; r2.x = __builtin_amdgcn_rcpf(d2.x);
                        r2.y = __builtin_amdgcn_rcpf(d2.y);
                hP = vfma(go2, r2, ngoh);         // h = 2*sig_o*r2 - sig_o
            }
            // re-broadcast h from the q==0 lane of each quad
            hP = dpp2<DPP_BC0>(hP);
        }
    }

    if (q == 0) {
        out[b * 8 + u]     = hP.x;
        out[b * 8 + u + 4] = hP.y;
    }
}

extern "C" void kernel_launch(void* const* d_in, const int* in_sizes, int n_in,
                              void* d_out, int out_size, void* d_ws, size_t ws_size,
                              hipStream_t stream) {
    const float* x   = (const float*)d_in[0];
    const float* h0  = (const float*)d_in[1];
    const float* c0  = (const float*)d_in[2];
    const float* Wih = (const float*)d_in[3];
    const float* Whh = (const float*)d_in[4];
    const float* bih = (const float*)d_in[5];
    const float* bhh = (const float*)d_in[6];
    float* out = (float*)d_out;

    dim3 grid(BATCH / 16);   // 256 blocks
    dim3 block(256);         // 16 groups of 16 lanes; 1024 waves = 1/SIMD
    hipLaunchKernelGGL(lstm_kernel, grid, block, 0, stream,
                       x, h0, c0, Wih, Whh, bih, bhh, out);
}